// Round 1
// 176.628 us; speedup vs baseline: 1.0081x; 1.0081x over previous
//
#include <hip/hip_runtime.h>

#define HW 16384
#define C 128

typedef __attribute__((ext_vector_type(8))) short short8;
typedef __attribute__((ext_vector_type(4))) float f32x4;
typedef __attribute__((ext_vector_type(2))) float f32x2;

__device__ __forceinline__ unsigned short f2bf(float f) {
  union { float f; unsigned u; } v; v.f = f;
  return (unsigned short)((v.u + 0x7fffu + ((v.u >> 16) & 1u)) >> 16);
}
#if __has_builtin(__builtin_amdgcn_cvt_pk_bf16_f32)
typedef __attribute__((ext_vector_type(2))) __bf16 bf16x2;
__device__ __forceinline__ unsigned pk2(float a, float b) {   // HW RNE pack
  union { bf16x2 v; unsigned u; } cv;
  cv.v = __builtin_amdgcn_cvt_pk_bf16_f32(a, b);
  return cv.u;
}
#else
__device__ __forceinline__ unsigned pk2(float a, float b) {   // SW RNE pack
  return (unsigned)f2bf(a) | ((unsigned)f2bf(b) << 16);
}
#endif
__device__ __forceinline__ unsigned short f2bf1(float a) {
  return (unsigned short)(pk2(a, a) & 0xffffu);
}
__device__ __forceinline__ float bflo(unsigned w) {
  union { unsigned u; float f; } v; v.u = w << 16; return v.f;
}
__device__ __forceinline__ float bfhi(unsigned w) {
  union { unsigned u; float f; } v; v.u = w & 0xffff0000u; return v.f;
}

// ---------------- Kernel 0: precompute Mt = C^-0.5 * Wk^T Wq  (row o, col c:
//   Mt[o][c] = s * sum_j Wk[j][o] * Wq[j][c]  == G[c][o] needed by q' GEMM),
//   P = Wproj @ Wv, both stored bf16 with the LDS XOR swizzle pre-applied,
//   plus the bilinear weight table pw/pi.  Grid: 257 blocks x 128 threads.
__global__ __launch_bounds__(128) void k_prep(const float* __restrict__ w_qkv,
                                              const float* __restrict__ w_proj,
                                              const float* __restrict__ delta,
                                              unsigned short* __restrict__ Mt,
                                              unsigned short* __restrict__ Pm,
                                              float* __restrict__ pw,
                                              int* __restrict__ pi) {
  const int bid = blockIdx.x;
  const int t = threadIdx.x;
  if (bid == 256) {
    if (t < 8) {
      float s0 = tanhf(delta[t * 2 + 0]) * 4.0f;  // col shift (x)
      float s1 = tanhf(delta[t * 2 + 1]) * 4.0f;  // row shift (y)
      float f0 = floorf(s0), f1 = floorf(s1);
      pi[2 * t + 0] = (int)f0;
      pi[2 * t + 1] = (int)f1;
      float fx = s0 - f0, fy = s1 - f1;
      pw[4 * t + 0] = (1.0f - fx) * (1.0f - fy);
      pw[4 * t + 1] = fx * (1.0f - fy);
      pw[4 * t + 2] = (1.0f - fx) * fy;
      pw[4 * t + 3] = fx * fy;
    }
    return;
  }
  const int R = bid & 127;
  float acc = 0.0f;
  if (bid < 128) {                         // Mt row R
    const float* wq = w_qkv;               // Wq[j][c]
    const float* wk = w_qkv + 128 * 128;   // Wk[j][o]
    #pragma unroll 16
    for (int j = 0; j < 128; ++j)
      acc += wk[j * 128 + R] * wq[j * 128 + t];   // wk: scalar, wq: coalesced
    acc *= 0.08838834764831845f;           // fold C^-0.5 into the logits
    Mt[R * 128 + (t ^ ((R & 7) << 3))] = f2bf1(acc);
  } else {                                 // P row R
    const float* wv = w_qkv + 2 * 128 * 128;  // Wv[j][c]
    const float* wp = w_proj + (size_t)R * 128;  // Wproj[R][j]
    #pragma unroll 16
    for (int j = 0; j < 128; ++j)
      acc += wp[j] * wv[j * 128 + t];
    Pm[R * 128 + (t ^ ((R & 7) << 3))] = f2bf1(acc);
  }
}

// ---------------- Kernel 1: q' = x * Mt GEMM + bf16 transposed copy of x -----
// One block per 128-pix tile.  Xs staged once (bf16, swizzled); while staging,
// the same bf16 pairs are written to global xq [pix][ch] for the gather kernel.
// Single GEMM phase (was 3 in the old k_qkv).
__global__ __launch_bounds__(256) void k_qx(const float* __restrict__ x,
                                            const unsigned short* __restrict__ Mt,
                                            unsigned short* __restrict__ qb,
                                            unsigned* __restrict__ xq) {
  __shared__ __align__(16) unsigned char smem[65536];
  unsigned short* Xs = (unsigned short*)smem;            // [pix][k] 32 KB
  unsigned short* Ws = (unsigned short*)(smem + 32768);  // [och][k] 32 KB
  const int t = threadIdx.x;
  const int gpix0 = blockIdx.x * 128;
  const int b = gpix0 >> 14;
  const int hw0 = gpix0 & (HW - 1);

  // stage Xs [pix][k] bf16, xor-swizzled; also emit xq = bf16(x) [pix][ch]
  const float* xb = x + (size_t)b * C * HW + hw0;
  #pragma unroll
  for (int i = 0; i < 16; ++i) {
    int linear = i * 256 + t;
    int p = linear & 127;
    int c4 = (linear >> 7) * 4;
    float a0 = xb[(size_t)(c4 + 0) * HW + p];
    float a1 = xb[(size_t)(c4 + 1) * HW + p];
    float a2 = xb[(size_t)(c4 + 2) * HW + p];
    float a3 = xb[(size_t)(c4 + 3) * HW + p];
    unsigned lo = pk2(a0, a1), hi = pk2(a2, a3);
    int cc = c4 ^ ((p & 7) << 3);
    *(uint2*)&Xs[p * 128 + cc] = make_uint2(lo, hi);
    *(uint2*)&xq[(size_t)(gpix0 + p) * 64 + (c4 >> 1)] = make_uint2(lo, hi);
  }
  // stage Ws: pre-swizzled bf16 Mt, straight 32 KB copy
  #pragma unroll
  for (int i = 0; i < 8; ++i)
    ((uint4*)Ws)[i * 256 + t] = ((const uint4*)Mt)[i * 256 + t];
  __syncthreads();

  const int wave = t >> 6, lane = t & 63;
  const int wr = wave >> 1, wc = wave & 1;
  const int rsel = lane & 15, quad = lane >> 4;

  f32x4 acc[4][4];
  #pragma unroll
  for (int mi = 0; mi < 4; ++mi)
    #pragma unroll
    for (int ni = 0; ni < 4; ++ni) acc[mi][ni] = (f32x4){0.f, 0.f, 0.f, 0.f};
  #pragma unroll
  for (int ks = 0; ks < 4; ++ks) {
    const int koff = ks * 32 + quad * 8;
    short8 afr[4], bfr[4];
    #pragma unroll
    for (int mi = 0; mi < 4; ++mi) {
      int r = wr * 64 + mi * 16 + rsel;
      afr[mi] = *(const short8*)&Xs[r * 128 + (koff ^ ((r & 7) << 3))];
    }
    #pragma unroll
    for (int ni = 0; ni < 4; ++ni) {
      int r = wc * 64 + ni * 16 + rsel;
      bfr[ni] = *(const short8*)&Ws[r * 128 + (koff ^ ((r & 7) << 3))];
    }
    #pragma unroll
    for (int mi = 0; mi < 4; ++mi)
      #pragma unroll
      for (int ni = 0; ni < 4; ++ni)
        acc[mi][ni] = __builtin_amdgcn_mfma_f32_16x16x32_bf16(afr[mi], bfr[ni], acc[mi][ni], 0, 0, 0);
  }
  #pragma unroll
  for (int mi = 0; mi < 4; ++mi)
    #pragma unroll
    for (int ni = 0; ni < 4; ++ni)
      #pragma unroll
      for (int r = 0; r < 4; ++r) {
        int pix = gpix0 + wr * 64 + mi * 16 + quad * 4 + r;
        int ch = wc * 64 + ni * 16 + rsel;
        qb[(size_t)pix * C + ch] = f2bf1(acc[mi][ni][r]);
      }
}

// ---------------- Kernel 2: fused gather + attention (bf16 x-samples) --------
// Same verified addressing as before; payload is now x-tilde (2 ch/lane/dword):
// logits = q'.x~ (scale pre-folded into Mt), out = sum_k softmax_k * x~_k.
__global__ __launch_bounds__(256) void k_attn(const unsigned short* __restrict__ qb,
                                              const unsigned* __restrict__ xq,
                                              const int* __restrict__ psf,
                                              const float* __restrict__ pw,
                                              const int* __restrict__ pi,
                                              unsigned short* __restrict__ ao) {
  const int t = threadIdx.x;
  const int lane = t & 63;
  const int p = blockIdx.x;
  const int b = (p >> 1) & 3;                    // batch -> XCD pair
  const int j = ((p >> 3) << 1) | (p & 1);
  const int spix = __builtin_amdgcn_readfirstlane((b << 14) + (j << 2) + (t >> 6));

  const unsigned* xB = xq + (size_t)b * HW * 64;  // SGPR base

  const unsigned qp = ((const unsigned*)qb)[(size_t)spix * 64 + lane];
  const float qx = bflo(qp), qy = bfhi(qp);

  int anch[16];
  #pragma unroll
  for (int jj = 0; jj < 16; ++jj) anch[jj] = psf[(size_t)spix * 16 + jj];

  float dk[8];
  float2 xt[8];
  #pragma unroll
  for (int k = 0; k < 8; ++k) {
    const int x0 = anch[k * 2 + 0] + pi[2 * k + 0], x1 = x0 + 1;  // SALU
    const int y0 = anch[k * 2 + 1] + pi[2 * k + 1], y1 = y0 + 1;
    float sx = 0, sy = 0;
    #pragma unroll
    for (int cn = 0; cn < 4; ++cn) {
      const int xi = (cn & 1) ? x1 : x0;
      const int yi = (cn & 2) ? y1 : y0;
      const bool valid = (xi >= 0) & (xi <= 127) & (yi >= 0) & (yi <= 127);
      const int xc = min(max(xi, 0), 127);
      const int yc = min(max(yi, 0), 127);
      const float wv = valid ? pw[k * 4 + cn] : 0.0f;              // scalar select
      const unsigned w = xB[(size_t)(yc * 128 + xc) * 64 + lane];  // 1 dword/corner
      sx += wv * bflo(w);
      sy += wv * bfhi(w);
    }
    xt[k] = make_float2(sx, sy);
    dk[k] = qx * sx + qy * sy;
  }
  #pragma unroll
  for (int off = 32; off > 0; off >>= 1) {
    #pragma unroll
    for (int k = 0; k < 8; ++k) dk[k] += __shfl_xor(dk[k], off);
  }
  float m = dk[0];
  #pragma unroll
  for (int k = 1; k < 8; ++k) m = fmaxf(m, dk[k]);
  float e[8], den = 0.0f;
  #pragma unroll
  for (int k = 0; k < 8; ++k) { e[k] = __expf(dk[k] - m); den += e[k]; }
  const float inv = 1.0f / den;
  float ox = 0, oy = 0;
  #pragma unroll
  for (int k = 0; k < 8; ++k) { float pk = e[k] * inv; ox += pk * xt[k].x; oy += pk * xt[k].y; }
  ((unsigned*)ao)[(size_t)spix * 64 + lane] = pk2(ox, oy);
}

// ---------------- Kernel 3: out = x + P @ ao  (bf16 MFMA, P = Wproj.Wv) ------
__global__ __launch_bounds__(256) void k_proj(const unsigned short* __restrict__ ao,
                                              const unsigned short* __restrict__ Pm,
                                              const float* __restrict__ x,
                                              float* __restrict__ out) {
  __shared__ __align__(16) unsigned short As[128 * 128];
  __shared__ __align__(16) unsigned short Ws[128 * 128];
  const int t = threadIdx.x;
  const int gpix0 = blockIdx.x * 128;
  const int b = gpix0 >> 14;
  const int hw0 = gpix0 & (HW - 1);

  #pragma unroll
  for (int i = 0; i < 8; ++i) {
    int linear = i * 256 + t;
    int c8 = (linear & 15) * 8;
    int p = linear >> 4;
    uint4 v = *(const uint4*)(ao + (size_t)(gpix0 + p) * C + c8);
    *(uint4*)&As[p * 128 + (c8 ^ ((p & 7) << 3))] = v;
  }
  #pragma unroll
  for (int i = 0; i < 8; ++i)
    ((uint4*)Ws)[i * 256 + t] = ((const uint4*)Pm)[i * 256 + t];
  __syncthreads();

  const int wave = t >> 6, lane = t & 63;
  const int wr = wave >> 1, wc = wave & 1;
  const int rsel = lane & 15, quad = lane >> 4;

  f32x4 acc[4][4];
  #pragma unroll
  for (int mi = 0; mi < 4; ++mi)
    #pragma unroll
    for (int ni = 0; ni < 4; ++ni) acc[mi][ni] = (f32x4){0.f, 0.f, 0.f, 0.f};

  #pragma unroll
  for (int ks = 0; ks < 4; ++ks) {
    const int koff = ks * 32 + quad * 8;
    short8 afr[4], bfr[4];
    #pragma unroll
    for (int mi = 0; mi < 4; ++mi) {
      int r = wr * 64 + mi * 16 + rsel;
      afr[mi] = *(const short8*)&Ws[r * 128 + (koff ^ ((r & 7) << 3))];
    }
    #pragma unroll
    for (int ni = 0; ni < 4; ++ni) {
      int r = wc * 64 + ni * 16 + rsel;
      bfr[ni] = *(const short8*)&As[r * 128 + (koff ^ ((r & 7) << 3))];
    }
    #pragma unroll
    for (int mi = 0; mi < 4; ++mi)
      #pragma unroll
      for (int ni = 0; ni < 4; ++ni)
        acc[mi][ni] = __builtin_amdgcn_mfma_f32_16x16x32_bf16(afr[mi], bfr[ni], acc[mi][ni], 0, 0, 0);
  }

  #pragma unroll
  for (int mi = 0; mi < 4; ++mi)
    #pragma unroll
    for (int ni = 0; ni < 4; ++ni)
      #pragma unroll
      for (int r = 0; r < 4; ++r) {
        int och = wr * 64 + mi * 16 + quad * 4 + r;
        int pixl = wc * 64 + ni * 16 + rsel;
        size_t addr = ((size_t)b * C + och) * HW + hw0 + pixl;
        out[addr] = x[addr] + acc[mi][ni][r];
      }
}

extern "C" void kernel_launch(void* const* d_in, const int* in_sizes, int n_in,
                              void* d_out, int out_size, void* d_ws, size_t ws_size,
                              hipStream_t stream) {
  const float* x      = (const float*)d_in[0];
  const int*   psf    = (const int*)d_in[1];
  const float* delta  = (const float*)d_in[2];
  const float* w_qkv  = (const float*)d_in[3];
  const float* w_proj = (const float*)d_in[4];
  float* out = (float*)d_out;

  const size_t N = (size_t)4 * HW * C;                 // 8388608 elems
  unsigned short* qb = (unsigned short*)d_ws;          // 16 MB bf16 q' [pix][ch]
  unsigned short* xq = qb + N;                         // 16 MB bf16 x~ [pix][ch]
  unsigned short* ao = xq + N;                         // 16 MB bf16 out-acc
  unsigned short* Mt = ao + N;                         // 32 KB bf16 swz
  unsigned short* Pm = Mt + 16384;                     // 32 KB bf16 swz
  float* pw = (float*)(Pm + 16384);                    // 32 floats
  int*   pi = (int*)(pw + 32);                         // 16 ints

  k_prep<<<dim3(257), 128, 0, stream>>>(w_qkv, w_proj, delta, Mt, Pm, pw, pi);
  k_qx<<<dim3(512), 256, 0, stream>>>(x, Mt, qb, (unsigned*)xq);
  k_attn<<<dim3(HW), 256, 0, stream>>>(qb, (const unsigned*)xq, psf, pw, pi, ao);
  k_proj<<<dim3(512), 256, 0, stream>>>(ao, Pm, x, out);
}

// Round 2
// 154.809 us; speedup vs baseline: 1.1502x; 1.1409x over previous
//
#include <hip/hip_runtime.h>

#define HW 16384
#define C 128

typedef __attribute__((ext_vector_type(8))) short short8;
typedef __attribute__((ext_vector_type(4))) float f32x4;
typedef __attribute__((ext_vector_type(2))) float f32x2;

__device__ __forceinline__ unsigned short f2bf(float f) {
  union { float f; unsigned u; } v; v.f = f;
  return (unsigned short)((v.u + 0x7fffu + ((v.u >> 16) & 1u)) >> 16);
}
#if __has_builtin(__builtin_amdgcn_cvt_pk_bf16_f32)
typedef __attribute__((ext_vector_type(2))) __bf16 bf16x2;
__device__ __forceinline__ unsigned pk2(float a, float b) {   // HW RNE pack
  union { bf16x2 v; unsigned u; } cv;
  cv.v = __builtin_amdgcn_cvt_pk_bf16_f32(a, b);
  return cv.u;
}
#else
__device__ __forceinline__ unsigned pk2(float a, float b) {   // SW RNE pack
  return (unsigned)f2bf(a) | ((unsigned)f2bf(b) << 16);
}
#endif
__device__ __forceinline__ unsigned short f2bf1(float a) {
  return (unsigned short)(pk2(a, a) & 0xffffu);
}
__device__ __forceinline__ float bflo(unsigned w) {
  union { unsigned u; float f; } v; v.u = w << 16; return v.f;
}
__device__ __forceinline__ float bfhi(unsigned w) {
  union { unsigned u; float f; } v; v.u = w & 0xffff0000u; return v.f;
}
__device__ __forceinline__ float asf(unsigned u) {
  union { unsigned u; float f; } v; v.u = u; return v.f;
}

// ---------------- Kernel 0: precompute Mt = C^-0.5 * Wk^T Wq, P = Wproj @ Wv,
// both stored bf16 with the LDS XOR swizzle pre-applied, plus bilinear pw/pi.
__global__ __launch_bounds__(128) void k_prep(const float* __restrict__ w_qkv,
                                              const float* __restrict__ w_proj,
                                              const float* __restrict__ delta,
                                              unsigned short* __restrict__ Mt,
                                              unsigned short* __restrict__ Pm,
                                              float* __restrict__ pw,
                                              int* __restrict__ pi) {
  const int bid = blockIdx.x;
  const int t = threadIdx.x;
  if (bid == 256) {
    if (t < 8) {
      float s0 = tanhf(delta[t * 2 + 0]) * 4.0f;  // col shift (x)
      float s1 = tanhf(delta[t * 2 + 1]) * 4.0f;  // row shift (y)
      float f0 = floorf(s0), f1 = floorf(s1);
      pi[2 * t + 0] = (int)f0;
      pi[2 * t + 1] = (int)f1;
      float fx = s0 - f0, fy = s1 - f1;
      pw[4 * t + 0] = (1.0f - fx) * (1.0f - fy);
      pw[4 * t + 1] = fx * (1.0f - fy);
      pw[4 * t + 2] = (1.0f - fx) * fy;
      pw[4 * t + 3] = fx * fy;
    }
    return;
  }
  const int R = bid & 127;
  float acc = 0.0f;
  if (bid < 128) {                         // Mt row R
    const float* wq = w_qkv;               // Wq[j][c]
    const float* wk = w_qkv + 128 * 128;   // Wk[j][o]
    #pragma unroll 16
    for (int j = 0; j < 128; ++j)
      acc += wk[j * 128 + R] * wq[j * 128 + t];   // wk: scalar, wq: coalesced
    acc *= 0.08838834764831845f;           // fold C^-0.5 into the logits
    Mt[R * 128 + (t ^ ((R & 7) << 3))] = f2bf1(acc);
  } else {                                 // P row R
    const float* wv = w_qkv + 2 * 128 * 128;  // Wv[j][c]
    const float* wp = w_proj + (size_t)R * 128;  // Wproj[R][j]
    #pragma unroll 16
    for (int j = 0; j < 128; ++j)
      acc += wp[j] * wv[j * 128 + t];
    Pm[R * 128 + (t ^ ((R & 7) << 3))] = f2bf1(acc);
  }
}

// ---------------- Kernel 1: q' = x * Mt GEMM + bf16 transposed copy of x -----
// Xs staged once (bf16, swizzled); xq emitted as a coalesced post-barrier LDS
// pass (uint4) instead of scattered 8B global stores.
__global__ __launch_bounds__(256) void k_qx(const float* __restrict__ x,
                                            const unsigned short* __restrict__ Mt,
                                            unsigned short* __restrict__ qb,
                                            unsigned* __restrict__ xq) {
  __shared__ __align__(16) unsigned char smem[65536];
  unsigned short* Xs = (unsigned short*)smem;            // [pix][k] 32 KB
  unsigned short* Ws = (unsigned short*)(smem + 32768);  // [och][k] 32 KB
  const int t = threadIdx.x;
  const int gpix0 = blockIdx.x * 128;
  const int b = gpix0 >> 14;
  const int hw0 = gpix0 & (HW - 1);

  // stage Xs [pix][k] bf16, xor-swizzled
  const float* xb = x + (size_t)b * C * HW + hw0;
  #pragma unroll
  for (int i = 0; i < 16; ++i) {
    int linear = i * 256 + t;
    int p = linear & 127;
    int c4 = (linear >> 7) * 4;
    float a0 = xb[(size_t)(c4 + 0) * HW + p];
    float a1 = xb[(size_t)(c4 + 1) * HW + p];
    float a2 = xb[(size_t)(c4 + 2) * HW + p];
    float a3 = xb[(size_t)(c4 + 3) * HW + p];
    int cc = c4 ^ ((p & 7) << 3);
    *(uint2*)&Xs[p * 128 + cc] = make_uint2(pk2(a0, a1), pk2(a2, a3));
  }
  // stage Ws: pre-swizzled bf16 Mt, straight 32 KB copy
  #pragma unroll
  for (int i = 0; i < 8; ++i)
    ((uint4*)Ws)[i * 256 + t] = ((const uint4*)Mt)[i * 256 + t];
  __syncthreads();

  // coalesced xq emit from staged Xs: [pix][64 dwords]
  #pragma unroll
  for (int i = 0; i < 8; ++i) {
    int linear = i * 256 + t;
    int c8 = (linear & 15) * 8;
    int prow = linear >> 4;
    uint4 v = *(const uint4*)&Xs[prow * 128 + (c8 ^ ((prow & 7) << 3))];
    *(uint4*)&xq[((size_t)(gpix0 + prow)) * 64 + (c8 >> 1)] = v;
  }

  const int wave = t >> 6, lane = t & 63;
  const int wr = wave >> 1, wc = wave & 1;
  const int rsel = lane & 15, quad = lane >> 4;

  f32x4 acc[4][4];
  #pragma unroll
  for (int mi = 0; mi < 4; ++mi)
    #pragma unroll
    for (int ni = 0; ni < 4; ++ni) acc[mi][ni] = (f32x4){0.f, 0.f, 0.f, 0.f};
  #pragma unroll
  for (int ks = 0; ks < 4; ++ks) {
    const int koff = ks * 32 + quad * 8;
    short8 afr[4], bfr[4];
    #pragma unroll
    for (int mi = 0; mi < 4; ++mi) {
      int r = wr * 64 + mi * 16 + rsel;
      afr[mi] = *(const short8*)&Xs[r * 128 + (koff ^ ((r & 7) << 3))];
    }
    #pragma unroll
    for (int ni = 0; ni < 4; ++ni) {
      int r = wc * 64 + ni * 16 + rsel;
      bfr[ni] = *(const short8*)&Ws[r * 128 + (koff ^ ((r & 7) << 3))];
    }
    #pragma unroll
    for (int mi = 0; mi < 4; ++mi)
      #pragma unroll
      for (int ni = 0; ni < 4; ++ni)
        acc[mi][ni] = __builtin_amdgcn_mfma_f32_16x16x32_bf16(afr[mi], bfr[ni], acc[mi][ni], 0, 0, 0);
  }
  #pragma unroll
  for (int mi = 0; mi < 4; ++mi)
    #pragma unroll
    for (int ni = 0; ni < 4; ++ni)
      #pragma unroll
      for (int r = 0; r < 4; ++r) {
        int pix = gpix0 + wr * 64 + mi * 16 + quad * 4 + r;
        int ch = wc * 64 + ni * 16 + rsel;
        qb[(size_t)pix * C + ch] = f2bf1(acc[mi][ni][r]);
      }
}

// ---------------- Kernel 2: fused gather + attention (bf16 x-samples) --------
// One wave per pixel. All per-corner address/clamp/valid/weight math forced
// into SALU via readfirstlane; VALU per corner = 2 extracts + 2 FMAs (SGPR wv).
__global__ __launch_bounds__(256) void k_attn(const unsigned short* __restrict__ qb,
                                              const unsigned* __restrict__ xq,
                                              const int* __restrict__ psf,
                                              const unsigned* __restrict__ pwu,
                                              const int* __restrict__ pi,
                                              unsigned short* __restrict__ ao) {
  const int t = threadIdx.x;
  const int lane = t & 63;
  const int p = blockIdx.x;
  const int b = (p >> 1) & 3;                    // batch -> XCD pair
  const int j = ((p >> 3) << 1) | (p & 1);
  const int spix = __builtin_amdgcn_readfirstlane((b << 14) + (j << 2) + (t >> 6));

  const unsigned* xB = xq + (size_t)b * HW * 64;  // SGPR base

  const unsigned qp = ((const unsigned*)qb)[(size_t)spix * 64 + lane];
  const float qx = bflo(qp), qy = bfhi(qp);

  // force anchors / shifts / weights into SGPRs so the whole per-corner
  // chain (adds, clamps, valid, select, gather base) issues on the SALU
  int anch[16];
  #pragma unroll
  for (int jj = 0; jj < 16; ++jj)
    anch[jj] = __builtin_amdgcn_readfirstlane(psf[(size_t)spix * 16 + jj]);
  int pis[16];
  #pragma unroll
  for (int jj = 0; jj < 16; ++jj)
    pis[jj] = __builtin_amdgcn_readfirstlane(pi[jj]);
  unsigned pws[32];
  #pragma unroll
  for (int jj = 0; jj < 32; ++jj)
    pws[jj] = __builtin_amdgcn_readfirstlane(pwu[jj]);

  float dk[8];
  float2 xt[8];
  #pragma unroll
  for (int k = 0; k < 8; ++k) {
    const int x0 = anch[k * 2 + 0] + pis[2 * k + 0];   // SALU
    const int y0 = anch[k * 2 + 1] + pis[2 * k + 1];
    float sx = 0.f, sy = 0.f;
    #pragma unroll
    for (int cn = 0; cn < 4; ++cn) {
      const int xi = x0 + (cn & 1);
      const int yi = y0 + (cn >> 1);
      const bool valid = (xi >= 0) & (xi <= 127) & (yi >= 0) & (yi <= 127);
      const int xc = min(max(xi, 0), 127);
      const int yc = min(max(yi, 0), 127);
      const unsigned wb = valid ? pws[k * 4 + cn] : 0u;   // s_cselect
      const float wv = asf(wb);                            // SGPR float
      const unsigned w = xB[((size_t)((yc << 7) + xc) << 6) + lane];  // s-base + lane
      sx = fmaf(bflo(w), wv, sx);
      sy = fmaf(bfhi(w), wv, sy);
    }
    xt[k] = make_float2(sx, sy);
    dk[k] = fmaf(qx, sx, qy * sy);
  }
  #pragma unroll
  for (int off = 32; off > 0; off >>= 1) {
    #pragma unroll
    for (int k = 0; k < 8; ++k) dk[k] += __shfl_xor(dk[k], off);
  }
  float m = dk[0];
  #pragma unroll
  for (int k = 1; k < 8; ++k) m = fmaxf(m, dk[k]);
  float e[8], den = 0.0f;
  #pragma unroll
  for (int k = 0; k < 8; ++k) { e[k] = __expf(dk[k] - m); den += e[k]; }
  const float inv = 1.0f / den;
  float ox = 0, oy = 0;
  #pragma unroll
  for (int k = 0; k < 8; ++k) { float pk = e[k] * inv; ox += pk * xt[k].x; oy += pk * xt[k].y; }
  ((unsigned*)ao)[(size_t)spix * 64 + lane] = pk2(ox, oy);
}

// ---------------- Kernel 3: out = x + P @ ao  (bf16 MFMA, P = Wproj.Wv) ------
__global__ __launch_bounds__(256) void k_proj(const unsigned short* __restrict__ ao,
                                              const unsigned short* __restrict__ Pm,
                                              const float* __restrict__ x,
                                              float* __restrict__ out) {
  __shared__ __align__(16) unsigned short As[128 * 128];
  __shared__ __align__(16) unsigned short Ws[128 * 128];
  const int t = threadIdx.x;
  const int gpix0 = blockIdx.x * 128;
  const int b = gpix0 >> 14;
  const int hw0 = gpix0 & (HW - 1);

  #pragma unroll
  for (int i = 0; i < 8; ++i) {
    int linear = i * 256 + t;
    int c8 = (linear & 15) * 8;
    int p = linear >> 4;
    uint4 v = *(const uint4*)(ao + (size_t)(gpix0 + p) * C + c8);
    *(uint4*)&As[p * 128 + (c8 ^ ((p & 7) << 3))] = v;
  }
  #pragma unroll
  for (int i = 0; i < 8; ++i)
    ((uint4*)Ws)[i * 256 + t] = ((const uint4*)Pm)[i * 256 + t];
  __syncthreads();

  const int wave = t >> 6, lane = t & 63;
  const int wr = wave >> 1, wc = wave & 1;
  const int rsel = lane & 15, quad = lane >> 4;

  f32x4 acc[4][4];
  #pragma unroll
  for (int mi = 0; mi < 4; ++mi)
    #pragma unroll
    for (int ni = 0; ni < 4; ++ni) acc[mi][ni] = (f32x4){0.f, 0.f, 0.f, 0.f};

  #pragma unroll
  for (int ks = 0; ks < 4; ++ks) {
    const int koff = ks * 32 + quad * 8;
    short8 afr[4], bfr[4];
    #pragma unroll
    for (int mi = 0; mi < 4; ++mi) {
      int r = wr * 64 + mi * 16 + rsel;
      afr[mi] = *(const short8*)&Ws[r * 128 + (koff ^ ((r & 7) << 3))];
    }
    #pragma unroll
    for (int ni = 0; ni < 4; ++ni) {
      int r = wc * 64 + ni * 16 + rsel;
      bfr[ni] = *(const short8*)&As[r * 128 + (koff ^ ((r & 7) << 3))];
    }
    #pragma unroll
    for (int mi = 0; mi < 4; ++mi)
      #pragma unroll
      for (int ni = 0; ni < 4; ++ni)
        acc[mi][ni] = __builtin_amdgcn_mfma_f32_16x16x32_bf16(afr[mi], bfr[ni], acc[mi][ni], 0, 0, 0);
  }

  #pragma unroll
  for (int mi = 0; mi < 4; ++mi)
    #pragma unroll
    for (int ni = 0; ni < 4; ++ni)
      #pragma unroll
      for (int r = 0; r < 4; ++r) {
        int och = wr * 64 + mi * 16 + quad * 4 + r;
        int pixl = wc * 64 + ni * 16 + rsel;
        size_t addr = ((size_t)b * C + och) * HW + hw0 + pixl;
        out[addr] = x[addr] + acc[mi][ni][r];
      }
}

extern "C" void kernel_launch(void* const* d_in, const int* in_sizes, int n_in,
                              void* d_out, int out_size, void* d_ws, size_t ws_size,
                              hipStream_t stream) {
  const float* x      = (const float*)d_in[0];
  const int*   psf    = (const int*)d_in[1];
  const float* delta  = (const float*)d_in[2];
  const float* w_qkv  = (const float*)d_in[3];
  const float* w_proj = (const float*)d_in[4];
  float* out = (float*)d_out;

  const size_t N = (size_t)4 * HW * C;                 // 8388608 elems
  unsigned short* qb = (unsigned short*)d_ws;          // 16 MB bf16 q' [pix][ch]
  unsigned short* xq = qb + N;                         // 16 MB bf16 x~ [pix][ch]
  unsigned short* ao = xq + N;                         // 16 MB bf16 out-acc
  unsigned short* Mt = ao + N;                         // 32 KB bf16 swz
  unsigned short* Pm = Mt + 16384;                     // 32 KB bf16 swz
  float* pw = (float*)(Pm + 16384);                    // 32 floats
  int*   pi = (int*)(pw + 32);                         // 16 ints

  k_prep<<<dim3(257), 128, 0, stream>>>(w_qkv, w_proj, delta, Mt, Pm, pw, pi);
  k_qx<<<dim3(512), 256, 0, stream>>>(x, Mt, qb, (unsigned*)xq);
  k_attn<<<dim3(HW), 256, 0, stream>>>(qb, (const unsigned*)xq, psf, (const unsigned*)pw, pi, ao);
  k_proj<<<dim3(512), 256, 0, stream>>>(ao, Pm, x, out);
}